// Round 4
// baseline (144.300 us; speedup 1.0000x reference)
//
#include <hip/hip_runtime.h>

// Problem constants
#define BB 256
#define GG 16
#define LL 16
#define CC 8192
#define KK 8
// GAMMA_NEG=4, GAMMA_POS=1, CLIP=0.05, EPS=1e-8

typedef float f32x4 __attribute__((ext_vector_type(4)));

#define NBLK (GG * BB)   // 4096

__device__ __forceinline__ float sigmoid_fast(float x) {
    float u = __expf(-x);                        // v_exp_f32
    return __builtin_amdgcn_rcpf(1.0f + u);      // v_rcp_f32
}

// target==0: t = max(s-0.05,0);  f_neg = -log(1-t) * t^4   (1-t >= 0.05 > EPS)
__device__ __forceinline__ float f_neg(float x) {
    float s  = sigmoid_fast(x);
    float t  = fmaxf(s - 0.05f, 0.0f);
    float l  = __logf(1.0f - t);
    float t2 = t * t;
    return -l * (t2 * t2);
}

// target==1: f_pos = -log(max(s,eps)) * (1-s)
__device__ __forceinline__ float f_pos(float x) {
    float s = sigmoid_fast(x);
    float l = __logf(fmaxf(s, 1e-8f));
    return -l * (1.0f - s);
}

// ---------------------------------------------------------------------------
// One block per (g,b) row (4096 blocks):
//  - streams its C=8192 row, summing f_neg               (coalesced float4)
//  - counts cnt[g,b] = #{l : param[b,l]>=0 && clip==g}   (wave 0, lanes 0..15)
//  - pos-correction for pair (b, l=g): <=8 scattered gathers on wave 0,
//    issued BEFORE the stream so the miss latency hides under it
//  partial[row] = cnt * rowsum + corrsum
// Last-arriving block (device-scope counter) reduces all partials -> mean.
// Deterministic: the final sum is computed in a fixed order by one block.
// ---------------------------------------------------------------------------
__global__ __launch_bounds__(256) void main_kernel(
    const float* __restrict__ logits, const int* __restrict__ param,
    const int* __restrict__ label, const int* __restrict__ num,
    float* __restrict__ partial, unsigned int* __restrict__ counter,
    float* __restrict__ out) {
    const int row = blockIdx.x;                  // g*BB + b
    const int g   = row >> 8;
    const int b   = row & (BB - 1);
    const int tid = threadIdx.x;

    // ---- wave-0 side work: issue all small/scattered loads first ----
    int   match   = 0;
    int   corr_on = 0;
    float xg      = 0.0f;
    if (tid < 64) {
        if (tid < LL) {                          // cnt contribution
            int pv = param[b * LL + tid];
            match = (pv >= 0) && (min(pv, GG - 1) == g);
        }
        const int t  = b * LL + g;               // this block's (b,l) pair
        const int pv = param[t];                 // broadcast load
        const int n  = min(num[t], KK);
        int myc = 0;
        if (tid < KK) myc = label[t * KK + tid];
        bool dup = false;                        // min(label_bit,1) clamp
#pragma unroll
        for (int j = 0; j < KK - 1; ++j) {
            int cj = __shfl(myc, j, 64);
            dup = dup || ((j < tid) && (cj == myc));
        }
        corr_on = (pv >= 0) && (tid < n) && !dup;
        if (corr_on) {
            const int p = min(pv, GG - 1);
            xg = logits[((size_t)p * BB + b) * CC + myc];   // scattered gather
        }
    }

    // ---- main streaming pass over row (g,b): 32 KB coalesced ----
    const f32x4* rp = reinterpret_cast<const f32x4*>(logits) + (size_t)row * (CC / 4);
    float acc = 0.0f;
#pragma unroll
    for (int i = 0; i < (CC / 4) / 256; ++i) {   // 8 iters
        f32x4 v = rp[tid + i * 256];
        acc += (f_neg(v.x) + f_neg(v.y)) + (f_neg(v.z) + f_neg(v.w));
    }
#pragma unroll
    for (int off = 32; off > 0; off >>= 1) acc += __shfl_down(acc, off, 64);
    __shared__ float sm[4];
    __shared__ int is_last;
    if ((tid & 63) == 0) sm[tid >> 6] = acc;
    __syncthreads();

    if (tid < 64) {
        float corr = corr_on ? (f_pos(xg) - f_neg(xg)) : 0.0f;
        int   cnt  = match;
#pragma unroll
        for (int off = 32; off > 0; off >>= 1) {
            corr += __shfl_down(corr, off, 64);
            cnt  += __shfl_down(cnt, off, 64);
        }
        if (tid == 0) {
            float rowsum = (sm[0] + sm[1]) + (sm[2] + sm[3]);
            partial[row] = (float)cnt * rowsum + corr;
            __threadfence();                     // release: write visible device-wide
            unsigned int old = atomicAdd(counter, 1u);
            is_last = (old == NBLK - 1);
        }
    }
    __syncthreads();

    if (is_last) {
        // acquire: invalidate caches so other XCDs' partials are seen
        __threadfence();
        float s = 0.0f;
#pragma unroll
        for (int i = 0; i < NBLK / 256; ++i)     // 16 coalesced rounds
            s += partial[tid + i * 256];
#pragma unroll
        for (int off = 32; off > 0; off >>= 1) s += __shfl_down(s, off, 64);
        __shared__ float sm2[4];
        if ((tid & 63) == 0) sm2[tid >> 6] = s;
        __syncthreads();
        if (tid == 0)
            out[0] = ((sm2[0] + sm2[1]) + (sm2[2] + sm2[3])) * (1.0f / (float)BB);
    }
}

extern "C" void kernel_launch(void* const* d_in, const int* in_sizes, int n_in,
                              void* d_out, int out_size, void* d_ws, size_t ws_size,
                              hipStream_t stream) {
    const float* logits = (const float*)d_in[0];   // (G, B, C) f32
    const int*   param  = (const int*)d_in[1];     // (B, L)
    const int*   label  = (const int*)d_in[2];     // (B, L, K)
    const int*   num    = (const int*)d_in[3];     // (B, L)
    float* out = (float*)d_out;
    float* partial = (float*)d_ws;                          // 4096 floats
    unsigned int* counter = (unsigned int*)((char*)d_ws + NBLK * sizeof(float));

    hipMemsetAsync(counter, 0, sizeof(unsigned int), stream);
    main_kernel<<<NBLK, 256, 0, stream>>>(logits, param, label, num,
                                          partial, counter, out);
}

// Round 5
// 116.271 us; speedup vs baseline: 1.2411x; 1.2411x over previous
//
#include <hip/hip_runtime.h>

// Problem constants
#define BB 256
#define GG 16
#define LL 16
#define CC 8192
#define KK 8
// GAMMA_NEG=4, GAMMA_POS=1, CLIP=0.05, EPS=1e-8

typedef float f32x4 __attribute__((ext_vector_type(4)));

#define NBLK (GG * BB)            // 4096
#define FIXSCALE 1048576.0f       // 2^20 fixed-point scale

__device__ __forceinline__ float sigmoid_fast(float x) {
    float u = __expf(-x);                        // v_exp_f32
    return __builtin_amdgcn_rcpf(1.0f + u);      // v_rcp_f32
}

// target==0: t = max(s-0.05,0);  f_neg = -log(1-t) * t^4   (1-t >= 0.05 > EPS)
__device__ __forceinline__ float f_neg(float x) {
    float s  = sigmoid_fast(x);
    float t  = fmaxf(s - 0.05f, 0.0f);
    float l  = __logf(1.0f - t);
    float t2 = t * t;
    return -l * (t2 * t2);
}

// target==1: f_pos = -log(max(s,eps)) * (1-s)
__device__ __forceinline__ float f_pos(float x) {
    float s = sigmoid_fast(x);
    float l = __logf(fmaxf(s, 1e-8f));
    return -l * (1.0f - s);
}

// ---------------------------------------------------------------------------
// One block per (g,b) row (4096 blocks):
//  - streams its C=8192 row, summing f_neg               (coalesced float4)
//  - counts cnt[g,b] = #{l : param[b,l]>=0 && clip==g}   (wave 0, lanes 0..15)
//  - pos-correction for pair (b, l=g): <=8 scattered gathers on wave 0,
//    issued BEFORE the stream so the miss latency hides under it
//  block partial = cnt * rowsum + corrsum  -> fixed-point i64 atomicAdd.
// NO fences anywhere: the payload travels through the atomic itself
// (R4 lesson: per-block __threadfence => L2-writeback storm, 6x slowdown).
// Integer accumulation => bit-deterministic independent of arrival order.
// ---------------------------------------------------------------------------
__global__ __launch_bounds__(256) void main_kernel(
    const float* __restrict__ logits, const int* __restrict__ param,
    const int* __restrict__ label, const int* __restrict__ num,
    unsigned long long* __restrict__ acc, unsigned int* __restrict__ counter,
    float* __restrict__ out) {
    const int row = blockIdx.x;                  // g*BB + b
    const int g   = row >> 8;
    const int b   = row & (BB - 1);
    const int tid = threadIdx.x;

    // ---- wave-0 side work: issue all small/scattered loads first ----
    int   match   = 0;
    int   corr_on = 0;
    float xg      = 0.0f;
    if (tid < 64) {
        if (tid < LL) {                          // cnt contribution
            int pv = param[b * LL + tid];
            match = (pv >= 0) && (min(pv, GG - 1) == g);
        }
        const int t  = b * LL + g;               // this block's (b,l) pair
        const int pv = param[t];                 // broadcast load
        const int n  = min(num[t], KK);
        int myc = 0;
        if (tid < KK) myc = label[t * KK + tid];
        bool dup = false;                        // min(label_bit,1) clamp
#pragma unroll
        for (int j = 0; j < KK - 1; ++j) {
            int cj = __shfl(myc, j, 64);
            dup = dup || ((j < tid) && (cj == myc));
        }
        corr_on = (pv >= 0) && (tid < n) && !dup;
        if (corr_on) {
            const int p = min(pv, GG - 1);
            xg = logits[((size_t)p * BB + b) * CC + myc];   // scattered gather
        }
    }

    // ---- main streaming pass over row (g,b): 32 KB coalesced ----
    const f32x4* rp = reinterpret_cast<const f32x4*>(logits) + (size_t)row * (CC / 4);
    float accv = 0.0f;
#pragma unroll
    for (int i = 0; i < (CC / 4) / 256; ++i) {   // 8 iters
        f32x4 v = rp[tid + i * 256];
        accv += (f_neg(v.x) + f_neg(v.y)) + (f_neg(v.z) + f_neg(v.w));
    }
#pragma unroll
    for (int off = 32; off > 0; off >>= 1) accv += __shfl_down(accv, off, 64);
    __shared__ float sm[4];
    if ((tid & 63) == 0) sm[tid >> 6] = accv;
    __syncthreads();

    if (tid < 64) {
        float corr = corr_on ? (f_pos(xg) - f_neg(xg)) : 0.0f;
        int   cnt  = match;
#pragma unroll
        for (int off = 32; off > 0; off >>= 1) {
            corr += __shfl_down(corr, off, 64);
            cnt  += __shfl_down(cnt, off, 64);
        }
        if (tid == 0) {
            float rowsum = (sm[0] + sm[1]) + (sm[2] + sm[3]);
            float partial = (float)cnt * rowsum + corr;
            // fixed-point payload: deterministic integer accumulation
            long long fx = llrintf(partial * FIXSCALE);
            atomicAdd(acc, (unsigned long long)fx);
            // ensure payload atomic is acknowledged before counter atomic
            asm volatile("s_waitcnt vmcnt(0)" ::: "memory");
            unsigned int old = atomicAdd(counter, 1u);
            if (old == NBLK - 1) {
                // all payload adds precede their counter adds -> total is final
                unsigned long long tot = atomicAdd(acc, 0ull);  // coherent read
                out[0] = (float)(long long)tot *
                         (1.0f / FIXSCALE) * (1.0f / (float)BB);
            }
        }
    }
}

extern "C" void kernel_launch(void* const* d_in, const int* in_sizes, int n_in,
                              void* d_out, int out_size, void* d_ws, size_t ws_size,
                              hipStream_t stream) {
    const float* logits = (const float*)d_in[0];   // (G, B, C) f32
    const int*   param  = (const int*)d_in[1];     // (B, L)
    const int*   label  = (const int*)d_in[2];     // (B, L, K)
    const int*   num    = (const int*)d_in[3];     // (B, L)
    float* out = (float*)d_out;
    unsigned long long* acc = (unsigned long long*)d_ws;        // 8 B
    unsigned int* counter   = (unsigned int*)((char*)d_ws + 8); // 4 B

    hipMemsetAsync(d_ws, 0, 16, stream);           // zero acc + counter
    main_kernel<<<NBLK, 256, 0, stream>>>(logits, param, label, num,
                                          acc, counter, out);
}

// Round 6
// 31.909 us; speedup vs baseline: 4.5222x; 3.6438x over previous
//
#include <hip/hip_runtime.h>

// Problem constants
#define BB 256
#define GG 16
#define LL 16
#define CC 8192
#define KK 8
// GAMMA_NEG=4, GAMMA_POS=1, CLIP=0.05, EPS=1e-8

typedef float f32x4 __attribute__((ext_vector_type(4)));

__device__ __forceinline__ float sigmoid_fast(float x) {
    float u = __expf(-x);                        // v_exp_f32
    return __builtin_amdgcn_rcpf(1.0f + u);      // v_rcp_f32
}

// target==0: t = max(s-0.05,0);  f_neg = -log(1-t) * t^4   (1-t >= 0.05 > EPS)
__device__ __forceinline__ float f_neg(float x) {
    float s  = sigmoid_fast(x);
    float t  = fmaxf(s - 0.05f, 0.0f);
    float l  = __logf(1.0f - t);
    float t2 = t * t;
    return -l * (t2 * t2);
}

// target==1: f_pos = -log(max(s,eps)) * (1-s)
__device__ __forceinline__ float f_pos(float x) {
    float s = sigmoid_fast(x);
    float l = __logf(fmaxf(s, 1e-8f));
    return -l * (1.0f - s);
}

// ---------------------------------------------------------------------------
// One block per (g,b) row (4096 blocks):
//  - streams its C=8192 row summing f_neg. All 8 float4 loads are issued
//    into registers BEFORE the math (R5 post-mortem: VGPR=20 showed the
//    compiler kept only ~2 loads in flight -> latency-bound stream).
//  - counts cnt[g,b] = #{l : param[b,l]>=0 && clip==g}   (wave 0)
//  - pos-correction for pair (b, l=g): <=8 scattered gathers on wave 0,
//    issued before the stream so their miss latency hides under it.
//  partial[row] = cnt * rowsum + corrsum     (plain store; kernel boundary
//  is the sync -- no fences, no atomics: R4/R5 showed both are disasters)
// ---------------------------------------------------------------------------
__global__ __launch_bounds__(256) void main_kernel(
    const float* __restrict__ logits, const int* __restrict__ param,
    const int* __restrict__ label, const int* __restrict__ num,
    float* __restrict__ partial) {
    const int row = blockIdx.x;                  // g*BB + b
    const int g   = row >> 8;
    const int b   = row & (BB - 1);
    const int tid = threadIdx.x;

    // ---- wave-0 side work: issue all small/scattered loads first ----
    int   match   = 0;
    int   corr_on = 0;
    float xg      = 0.0f;
    if (tid < 64) {
        if (tid < LL) {                          // cnt contribution
            int pv = param[b * LL + tid];
            match = (pv >= 0) && (min(pv, GG - 1) == g);
        }
        const int t  = b * LL + g;               // this block's (b,l) pair
        const int pv = param[t];                 // broadcast load
        const int n  = min(num[t], KK);
        int myc = 0;
        if (tid < KK) myc = label[t * KK + tid];
        bool dup = false;                        // min(label_bit,1) clamp
#pragma unroll
        for (int j = 0; j < KK - 1; ++j) {
            int cj = __shfl(myc, j, 64);
            dup = dup || ((j < tid) && (cj == myc));
        }
        corr_on = (pv >= 0) && (tid < n) && !dup;
        if (corr_on) {
            const int p = min(pv, GG - 1);
            xg = logits[((size_t)p * BB + b) * CC + myc];   // scattered gather
        }
    }

    // ---- main streaming pass over row (g,b): 32 KB coalesced ----
    const f32x4* rp = reinterpret_cast<const f32x4*>(logits) + (size_t)row * (CC / 4);
    f32x4 v[8];
#pragma unroll
    for (int i = 0; i < 8; ++i) v[i] = rp[tid + i * 256];   // 8 loads in flight
    float a0 = 0.0f, a1 = 0.0f, a2 = 0.0f, a3 = 0.0f;       // 4 indep chains
#pragma unroll
    for (int i = 0; i < 8; ++i) {
        a0 += f_neg(v[i].x); a1 += f_neg(v[i].y);
        a2 += f_neg(v[i].z); a3 += f_neg(v[i].w);
    }
    float accv = (a0 + a1) + (a2 + a3);
#pragma unroll
    for (int off = 32; off > 0; off >>= 1) accv += __shfl_down(accv, off, 64);
    __shared__ float sm[4];
    if ((tid & 63) == 0) sm[tid >> 6] = accv;
    __syncthreads();

    if (tid < 64) {
        float corr = corr_on ? (f_pos(xg) - f_neg(xg)) : 0.0f;
        int   cnt  = match;
#pragma unroll
        for (int off = 32; off > 0; off >>= 1) {
            corr += __shfl_down(corr, off, 64);
            cnt  += __shfl_down(cnt, off, 64);
        }
        if (tid == 0) {
            float rowsum = (sm[0] + sm[1]) + (sm[2] + sm[3]);
            partial[row] = (float)cnt * rowsum + corr;
        }
    }
}

// ---------------------------------------------------------------------------
// Final: reduce 4096 partials -> mean over B. Fixed-order tree: deterministic.
// ---------------------------------------------------------------------------
__global__ __launch_bounds__(1024) void reduce_kernel(
    const float* __restrict__ partial, float* __restrict__ out) {
    const f32x4 v = reinterpret_cast<const f32x4*>(partial)[threadIdx.x];
    float s = (v.x + v.y) + (v.z + v.w);
#pragma unroll
    for (int off = 32; off > 0; off >>= 1) s += __shfl_down(s, off, 64);
    __shared__ float sm[16];
    if ((threadIdx.x & 63) == 0) sm[threadIdx.x >> 6] = s;
    __syncthreads();
    if (threadIdx.x < 64) {
        float v2 = (threadIdx.x < 16) ? sm[threadIdx.x] : 0.0f;
#pragma unroll
        for (int off = 8; off > 0; off >>= 1) v2 += __shfl_down(v2, off, 64);
        if (threadIdx.x == 0) out[0] = v2 * (1.0f / (float)BB);
    }
}

extern "C" void kernel_launch(void* const* d_in, const int* in_sizes, int n_in,
                              void* d_out, int out_size, void* d_ws, size_t ws_size,
                              hipStream_t stream) {
    const float* logits = (const float*)d_in[0];   // (G, B, C) f32
    const int*   param  = (const int*)d_in[1];     // (B, L)
    const int*   label  = (const int*)d_in[2];     // (B, L, K)
    const int*   num    = (const int*)d_in[3];     // (B, L)
    float* out = (float*)d_out;
    float* partial = (float*)d_ws;                 // 4096 floats

    main_kernel<<<GG * BB, 256, 0, stream>>>(logits, param, label, num, partial);
    reduce_kernel<<<1, 1024, 0, stream>>>(partial, out);
}